// Round 3
// baseline (407.263 us; speedup 1.0000x reference)
//
#include <hip/hip_runtime.h>
#include <stdint.h>

// Problem: DynamicVoxelizer. B=8, N=1e6, voxel=0.2, grid (x,y,z)=(512,512,30).
// d_out = FLOAT32 x 88,000,000, concatenated:
//   [0,24M) out_points  [24M,48M) coords_zyx  [48M,56M) idx
//   [56M,80M) offsets   [80M,88M) valid
// History: R3 424us, R5 nt neutral, R6 LDS-staged vec3 stores 407us,
// R7 strided mapping 407.5, R8 VALU cut NEUTRAL, R9 occupancy 100% NEUTRAL.
// => kernel (~97us, 4.6 TB/s eff) is pinned by the two-phase __syncthreads
// structure: compiler emits s_waitcnt vmcnt(0) before s_barrier, so every
// block drains ALL global loads+stores (write-ack latency) at the barrier,
// phase-locking the CU's memory pipeline. Occupancy/VALU can't fix that.
// R10 (this): the transpose is WAVE-LOCAL (wave w iter j owns 64 consecutive
// points = 192 consecutive floats per region). Per-wave LDS slices +
// wave_barrier() (free compiler fence; DS ops of a wave complete in-order
// at the LDS unit) + same-wave 48-lane fx4 stores. No __syncthreads, no
// vmcnt(0) drain anywhere: waves are independent fire-and-forget pipelines.

#define NPB   1000000
#define TOT   8000000
#define BLK   256
#define PPT   2
#define PPB   (BLK * PPT)                 // 512 points per block
#define NBLK  (TOT / PPB)                 // 15625, exact (no partial block)
#define NW    (BLK / 64)                  // 4 waves per block

typedef float fx4 __attribute__((ext_vector_type(4)));

__global__ __launch_bounds__(256, 8) void voxelize_kernel(
        const float* __restrict__ pts, float* __restrict__ out) {
    // Per-wave slices, reused across j (wave-private => no cross-wave hazard;
    // own-wave DS ordering makes j=0 reads complete before j=1 writes).
    // 192 floats/wave/region; 4 waves; 3 regions = 9 KB total.
    __shared__ __attribute__((aligned(16))) float lsA[NW * 192];  // out_points
    __shared__ __attribute__((aligned(16))) float lsB[NW * 192];  // coords_zyx
    __shared__ __attribute__((aligned(16))) float lsC[NW * 192];  // offsets

    const int t = threadIdx.x;
    const int w = t >> 6;            // wave id (0..3)
    const int l = t & 63;            // lane   (0..63)
    const uint32_t P0 = (uint32_t)blockIdx.x * PPB;

    // Exact-division replacement (verified R8/R9): R = correctly-rounded
    // double reciprocal of (double)0.2f; (float)((double)a * R) == a / 0.2f
    // in fp32 except within ~2^-52 rel of a rounding boundary.
    const double R = 1.0 / (double)0.2f;

    // Batch-local index: one magic-div per thread, then increment.
    const uint32_t n0  = P0 + (uint32_t)t;
    const uint32_t b0  = n0 / NPB;             // magic-mul
    const uint32_t ni0 = n0 - b0 * NPB;

    float* lA = lsA + w * 192;
    float* lB = lsB + w * 192;
    float* lC = lsC + w * 192;

#pragma unroll
    for (int j = 0; j < PPT; ++j) {
        // Wave w handles points P0 + j*256 + 64w + lane  (== P0 + j*256 + t)
        uint32_t n  = P0 + (uint32_t)(j * BLK) + (uint32_t)t;   // < TOT always
        uint32_t ni = ni0 + (uint32_t)(j * BLK);
        if (ni >= NPB) ni -= NPB;        // single wrap fix

        // 12B/lane contiguous load (compiler merges to dwordx3)
        const float* pp = pts + (size_t)n * 3;
        float x = pp[0], y = pp[1], z = pp[2];

        bool nn = (x == x) && (y == y) && (z == z);
        float px = nn ? x : 0.0f;
        float py = nn ? y : 0.0f;
        float pz = nn ? z : 0.0f;

        float tx = (float)((double)(px + 51.2f) * R);
        float ty = (float)((double)(py + 51.2f) * R);
        float tz = (float)((double)(pz + 3.0f)  * R);

        // Float-domain range check: 0 <= floor(t) < G  <=>  0 <= t < G.
        bool valid = nn && (tx >= 0.0f) && (tx < 512.0f)
                        && (ty >= 0.0f) && (ty < 512.0f)
                        && (tz >= 0.0f) && (tz < 30.0f);

        // truncf == floorf for t >= 0; negative-t lanes are invalid and all
        // their outputs are forced by the `valid` selects below.
        float fcx = truncf(tx);
        float fcy = truncf(ty);
        float fcz = truncf(tz);

        float ctx = (fcx * 0.2f + (-51.2f)) + 0.1f;
        float cty = (fcy * 0.2f + (-51.2f)) + 0.1f;
        float ctz = (fcz * 0.2f + (-3.0f))  + 0.1f;

        // Wave-private LDS staging: 12B/lane, 2-way bank alias only (free)
        lA[3*l+0] = valid ? px : 0.0f;
        lA[3*l+1] = valid ? py : 0.0f;
        lA[3*l+2] = valid ? pz : 0.0f;
        lB[3*l+0] = valid ? fcz : -1.0f;   // zyx order
        lB[3*l+1] = valid ? fcy : -1.0f;
        lB[3*l+2] = valid ? fcx : -1.0f;
        lC[3*l+0] = valid ? (px - ctx) : 0.0f;
        lC[3*l+1] = valid ? (py - cty) : 0.0f;
        lC[3*l+2] = valid ? (pz - ctz) : 0.0f;

        // Compiler fence only (no HW cost): keep the ds_writes above the
        // ds_reads below. Cross-lane visibility is guaranteed by in-order
        // DS processing within a wave.
        __builtin_amdgcn_wave_barrier();

        // Same-wave transpose consume: lanes 0..47 store 48 fx4 = the wave's
        // 192 floats per region, lane-contiguous at the fx4 granularity.
        if (l < 48) {
            fx4 a = ((const fx4*)lA)[l];
            fx4 c = ((const fx4*)lB)[l];
            fx4 o = ((const fx4*)lC)[l];
            // float base = 3*(P0 + j*256 + 64w) ; /4 => fx4 index:
            size_t f4i = (size_t)blockIdx.x * (PPB * 3 / 4)
                       + (size_t)(j * 192 + w * 48 + l);
            ((fx4*)(out))[f4i]                    = a;
            ((fx4*)(out + (size_t)24000000))[f4i] = c;
            ((fx4*)(out + (size_t)56000000))[f4i] = o;
        }

        // Scalar regions: 4B/lane contiguous dword stores (fire and forget)
        out[(size_t)48000000 + n] = valid ? (float)ni : -1.0f;
        out[(size_t)80000000 + n] = valid ? 1.0f : 0.0f;

        // Fence before next iteration's ds_writes reuse the slice.
        __builtin_amdgcn_wave_barrier();
    }
}

extern "C" void kernel_launch(void* const* d_in, const int* in_sizes, int n_in,
                              void* d_out, int out_size, void* d_ws, size_t ws_size,
                              hipStream_t stream) {
    const float* pts = (const float*)d_in[0];
    float* out = (float*)d_out;
    voxelize_kernel<<<NBLK, BLK, 0, stream>>>(pts, out);
}